// Round 6
// baseline (233.343 us; speedup 1.0000x reference)
//
#include <hip/hip_runtime.h>
#include <stdint.h>
#include <math.h>

#define B_ 2
#define S_ 2048
#define D_ 1024
#define H_ 16
#define HD_ 64
#define KVBLK 64

typedef __bf16 bf16_t;
typedef __bf16 bf16x4 __attribute__((ext_vector_type(4)));
typedef __bf16 bf16x8 __attribute__((ext_vector_type(8)));
typedef float f32x4 __attribute__((ext_vector_type(4)));
typedef float f32x16 __attribute__((ext_vector_type(16)));
typedef float float4v __attribute__((ext_vector_type(4)));

#define L2E 1.4426950408889634f
#define NINF (-__builtin_inff())

__device__ __forceinline__ void gload_lds16(const bf16_t* g, bf16_t* l) {
  __builtin_amdgcn_global_load_lds((const __attribute__((address_space(1))) void*)g,
                                   (__attribute__((address_space(3))) void*)l, 16, 0, 0);
}

__device__ __forceinline__ uint32_t packbf(float a, float b) {
  union { __bf16 h[2]; uint32_t u; } cvt;
  cvt.h[0] = (__bf16)a; cvt.h[1] = (__bf16)b;
  return cvt.u;
}

// ---------------- cast f32 -> bf16 (vector x4) ----------------
__global__ void cast_bf16_kernel(const float* __restrict__ src, bf16_t* __restrict__ dst, int n4) {
  int i = blockIdx.x * blockDim.x + threadIdx.x;
  int stride = gridDim.x * blockDim.x;
  for (; i < n4; i += stride) {
    float4v f = *(const float4v*)(src + (size_t)i * 4);
    bf16x4 o;
    o[0] = (__bf16)f[0]; o[1] = (__bf16)f[1]; o[2] = (__bf16)f[2]; o[3] = (__bf16)f[3];
    *(bf16x4*)(dst + (size_t)i * 4) = o;
  }
}

// ---------------- GEMM: C[m][n] = sum_k A[m][k] * B[n][k] ----------------
template <typename OutT>
__global__ __launch_bounds__(256) void gemm_bt(const bf16_t* __restrict__ A,
                                               const bf16_t* __restrict__ Bm,
                                               OutT* __restrict__ C,
                                               int M, int N, int K) {
  __shared__ bf16_t As[128 * 32];
  __shared__ bf16_t Bs[128 * 32];
  const int t = threadIdx.x;
  const int lane = t & 63, wave = t >> 6;
  const int wr = wave >> 1, wc = wave & 1;
  const int qr = lane & 15, g = lane >> 4;
  const int bm = blockIdx.x, bn = blockIdx.y;

  f32x4 acc[4][4];
#pragma unroll
  for (int m = 0; m < 4; m++)
#pragma unroll
    for (int n = 0; n < 4; n++) acc[m][n] = (f32x4){0.f, 0.f, 0.f, 0.f};

  const bf16_t* Abase = A + (size_t)(bm * 128) * K;
  const bf16_t* Bbase = Bm + (size_t)(bn * 128) * K;
  const int srow = t >> 2;
  const int scol = (t & 3) * 8;

  for (int kk = 0; kk < K; kk += 32) {
    gload_lds16(Abase + (size_t)srow * K + kk + scol,        As + t * 8);
    gload_lds16(Abase + (size_t)(srow + 64) * K + kk + scol, As + 2048 + t * 8);
    gload_lds16(Bbase + (size_t)srow * K + kk + scol,        Bs + t * 8);
    gload_lds16(Bbase + (size_t)(srow + 64) * K + kk + scol, Bs + 2048 + t * 8);
    __syncthreads();
    bf16x8 a[4], b[4];
#pragma unroll
    for (int m = 0; m < 4; m++)
      a[m] = *(const bf16x8*)(As + (wr * 64 + m * 16 + qr) * 32 + g * 8);
#pragma unroll
    for (int n = 0; n < 4; n++)
      b[n] = *(const bf16x8*)(Bs + (wc * 64 + n * 16 + qr) * 32 + g * 8);
#pragma unroll
    for (int m = 0; m < 4; m++)
#pragma unroll
      for (int n = 0; n < 4; n++)
        acc[m][n] = __builtin_amdgcn_mfma_f32_16x16x32_bf16(a[m], b[n], acc[m][n], 0, 0, 0);
    __syncthreads();
  }

#pragma unroll
  for (int m = 0; m < 4; m++) {
    int row0 = bm * 128 + wr * 64 + m * 16 + g * 4;
#pragma unroll
    for (int n = 0; n < 4; n++) {
      int col = bn * 128 + wc * 64 + n * 16 + qr;
#pragma unroll
      for (int r = 0; r < 4; r++)
        C[(size_t)(row0 + r) * N + col] = (OutT)acc[m][n][r];
    }
  }
}

// ---------------- RoPE on q,k + q-scale; writes Q,K as [B][H][S][HD] bf16 ----------------
__global__ void rope_qk_kernel(const bf16_t* __restrict__ qkv, const int* __restrict__ pos,
                               bf16_t* __restrict__ Q, bf16_t* __restrict__ Ko) {
  int idx = blockIdx.x * blockDim.x + threadIdx.x;
  if (idx >= B_ * S_ * H_ * 32) return;
  int i = idx & 31;
  int h = (idx >> 5) & (H_ - 1);
  int bs = idx >> 9;
  const bf16_t* row = qkv + (size_t)bs * (3 * D_) + h * 192;
  float q1 = (float)row[i], q2 = (float)row[i + 32];
  float k1 = (float)row[64 + i], k2 = (float)row[96 + i];
  int p = pos[bs];
  float inv = exp2f(-(float)i * (13.287712379549449f / 32.0f));
  float ang = (float)p * inv;
  float sn, cs;
  sincosf(ang, &sn, &cs);
  float qo1 = (q1 * cs - q2 * sn) * 0.125f;
  float qo2 = (q2 * cs + q1 * sn) * 0.125f;
  float ko1 = k1 * cs - k2 * sn;
  float ko2 = k2 * cs + k1 * sn;
  int b = bs >> 11, s = bs & (S_ - 1);
  size_t o = ((size_t)(b * H_ + h) * S_ + s) * HD_ + i;
  Q[o] = (__bf16)qo1;  Q[o + 32] = (__bf16)qo2;
  Ko[o] = (__bf16)ko1; Ko[o + 32] = (__bf16)ko2;
}

// ---------------- V transpose: qkv v-slice -> Vt [B][H][HD][S] bf16 ----------------
__global__ __launch_bounds__(256) void v_transpose_kernel(const bf16_t* __restrict__ qkv,
                                                          bf16_t* __restrict__ Vt) {
  __shared__ bf16_t tile[64][72];
  int t = threadIdx.x;
  int s0 = blockIdx.x * 64;
  int h = blockIdx.y, b = blockIdx.z;
  int sl = t >> 4;
  int cb = (t & 15) * 4;
#pragma unroll
  for (int it = 0; it < 4; it++) {
    int s = sl + it * 16;
    const bf16_t* src = qkv + (size_t)(b * S_ + s0 + s) * (3 * D_) + h * 192 + 128 + cb;
    bf16x4 v = *(const bf16x4*)src;
    tile[cb + 0][s] = v[0]; tile[cb + 1][s] = v[1];
    tile[cb + 2][s] = v[2]; tile[cb + 3][s] = v[3];
  }
  __syncthreads();
#pragma unroll
  for (int it = 0; it < 4; it++) {
    int d = sl + it * 16;
    bf16x4 v;
    v[0] = tile[d][cb]; v[1] = tile[d][cb + 1]; v[2] = tile[d][cb + 2]; v[3] = tile[d][cb + 3];
    *(bf16x4*)(Vt + ((size_t)((b * H_ + h) * HD_ + d)) * S_ + s0 + cb) = v;
  }
}

// ---------------- flash attention: barrier-free 1-wave blocks + in-register K/V dbuf ----------------
// grid: (S/32, H, B), bx reversed (heavy first). 64 threads = 1 wave owning 32 q-rows.
// Swapped QK^T: S^T = K*Q^T (lane owns q-column l31); swapped PV: O^T = V^T*P.
// K/V double-buffered in REGISTERS (two named sets, static indexing): tile t+1's loads
// issue before compute(t); waitcnt lands at compute(t+1)'s first use -> latency hidden.
__global__ __launch_bounds__(64, 2) void attn_kernel(const bf16_t* __restrict__ Q,
                                                     const bf16_t* __restrict__ K,
                                                     const bf16_t* __restrict__ Vt,
                                                     const int* __restrict__ pos,
                                                     bf16_t* __restrict__ O) {
  __shared__ bf16_t Ot[32 * 64];   // epilogue transpose scratch (16B-chunk XOR swizzled)

  const int lane = threadIdx.x;
  const int l31 = lane & 31, hi = lane >> 5;
  const int h = blockIdx.y, b = blockIdx.z;
  const int qblk = gridDim.x - 1 - blockIdx.x;   // reversed: longest blocks first
  const int q0 = qblk * 32;

  const size_t bh = (size_t)(b * H_ + h);
  const bf16_t* Qb = Q + bh * (S_ * HD_);
  const bf16_t* Kb = K + bh * (S_ * HD_);
  const bf16_t* Vb = Vt + bh * (HD_ * S_);

  // Q fragments (B-operand): lane holds row q = q0+l31, d = c*16 + 8*hi + j
  const int qrow = q0 + l31;
  bf16x8 qf[4];
#pragma unroll
  for (int c = 0; c < 4; c++)
    qf[c] = *(const bf16x8*)(Qb + (size_t)qrow * HD_ + c * 16 + hi * 8);

  const int prow = pos[b * S_ + qrow];
  int wmin = prow, mp = prow;
#pragma unroll
  for (int off = 1; off < 32; off <<= 1) {
    wmin = min(wmin, __shfl_xor(wmin, off));
    mp = max(mp, __shfl_xor(mp, off));
  }
  const int ntiles = min(S_ / KVBLK, (mp >> 6) + 1);

  f32x16 oT[2];
#pragma unroll
  for (int dt = 0; dt < 2; dt++)
#pragma unroll
    for (int r = 0; r < 16; r++) oT[dt][r] = 0.f;
  float m_run = NINF, l_run = 0.f;

  auto load_tile = [&](int kt, bf16x8 (&kf0)[4], bf16x8 (&kf1)[4],
                       bf16x8 (&vf0)[4], bf16x8 (&vf1)[4]) {
    const int k0 = kt * KVBLK;
#pragma unroll
    for (int c = 0; c < 4; c++) {
      kf0[c] = *(const bf16x8*)(Kb + (size_t)(k0 + l31) * HD_ + (c * 2 + hi) * 8);
      kf1[c] = *(const bf16x8*)(Kb + (size_t)(k0 + 32 + l31) * HD_ + (c * 2 + hi) * 8);
    }
#pragma unroll
    for (int kc = 0; kc < 4; kc++) {
      vf0[kc] = *(const bf16x8*)(Vb + (size_t)l31 * S_ + k0 + (kc * 2 + hi) * 8);
      vf1[kc] = *(const bf16x8*)(Vb + (size_t)(32 + l31) * S_ + k0 + (kc * 2 + hi) * 8);
    }
  };

  auto compute_tile = [&](int kt, const bf16x8 (&kf0)[4], const bf16x8 (&kf1)[4],
                          const bf16x8 (&vf0)[4], const bf16x8 (&vf1)[4]) {
    const int k0 = kt * KVBLK;

    // QK^T swapped: s0 = K[k0..k0+31] x Q^T, s1 = K[k0+32..k0+63] x Q^T
    f32x16 s0, s1;
#pragma unroll
    for (int r = 0; r < 16; r++) { s0[r] = 0.f; s1[r] = 0.f; }
    __builtin_amdgcn_s_setprio(1);
#pragma unroll
    for (int c = 0; c < 4; c++) {
      s0 = __builtin_amdgcn_mfma_f32_32x32x16_bf16(kf0[c], qf[c], s0, 0, 0, 0);
      s1 = __builtin_amdgcn_mfma_f32_32x32x16_bf16(kf1[c], qf[c], s1, 0, 0, 0);
    }
    __builtin_amdgcn_s_setprio(0);

    // causal mask (skip when tile fully visible for this wave)
    float p0[16], p1[16];
    if (k0 + 63 > wmin) {
#pragma unroll
      for (int r = 0; r < 16; r++) {
        int koff = (r & 3) + 8 * (r >> 2) + 4 * hi;
        p0[r] = (k0 + koff <= prow) ? s0[r] : NINF;
        p1[r] = (k0 + 32 + koff <= prow) ? s1[r] : NINF;
      }
    } else {
#pragma unroll
      for (int r = 0; r < 16; r++) { p0[r] = s0[r]; p1[r] = s1[r]; }
    }

    // per-lane online softmax with defer-max (T13, THR=8); cross-half via shfl
    float tm = NINF;
#pragma unroll
    for (int r = 0; r < 16; r++) tm = fmaxf(tm, fmaxf(p0[r], p1[r]));
    tm = fmaxf(tm, __shfl_xor(tm, 32));
    if (__any(tm > m_run + 8.0f)) {
      float mn = fmaxf(fmaxf(m_run, tm), -1e30f);
      float scale = exp2f((m_run - mn) * L2E);
      l_run *= scale;
#pragma unroll
      for (int dt = 0; dt < 2; dt++)
#pragma unroll
        for (int r = 0; r < 16; r++) oT[dt][r] *= scale;
      m_run = mn;
    }
    const float mnl = m_run * L2E;
    float rs = 0.f;
#pragma unroll
    for (int r = 0; r < 16; r++) {
      p0[r] = exp2f(p0[r] * L2E - mnl);
      p1[r] = exp2f(p1[r] * L2E - mnl);
      rs += p0[r] + p1[r];
    }
    rs += __shfl_xor(rs, 32);
    l_run += rs;

    // PV swapped: oT[dt] += V^T(32d x 16k) x P(16k x 32q); P via shfl_xor(,32)+select
#pragma unroll
    for (int kc = 0; kc < 4; kc++) {
      const float* P = (kc < 2) ? p0 : p1;
      const int rb = (kc & 1) * 8;
      uint32_t xa0 = packbf(P[rb + 0], P[rb + 1]);
      uint32_t xa1 = packbf(P[rb + 2], P[rb + 3]);
      uint32_t xb0 = packbf(P[rb + 4], P[rb + 5]);
      uint32_t xb1 = packbf(P[rb + 6], P[rb + 7]);
      uint32_t sa0 = (uint32_t)__shfl_xor((int)xa0, 32);
      uint32_t sa1 = (uint32_t)__shfl_xor((int)xa1, 32);
      uint32_t sb0 = (uint32_t)__shfl_xor((int)xb0, 32);
      uint32_t sb1 = (uint32_t)__shfl_xor((int)xb1, 32);
      union { uint32_t u[4]; bf16x8 v; } pf;
      pf.u[0] = hi ? sb0 : xa0;
      pf.u[1] = hi ? sb1 : xa1;
      pf.u[2] = hi ? xb0 : sa0;
      pf.u[3] = hi ? xb1 : sa1;
      __builtin_amdgcn_s_setprio(1);
      oT[0] = __builtin_amdgcn_mfma_f32_32x32x16_bf16(vf0[kc], pf.v, oT[0], 0, 0, 0);
      oT[1] = __builtin_amdgcn_mfma_f32_32x32x16_bf16(vf1[kc], pf.v, oT[1], 0, 0, 0);
      __builtin_amdgcn_s_setprio(0);
    }
  };

  // in-register double-buffer pipeline (two named sets; all indexing static)
  bf16x8 kA0[4], kA1[4], vA0[4], vA1[4];
  bf16x8 kB0[4], kB1[4], vB0[4], vB1[4];
  load_tile(0, kA0, kA1, vA0, vA1);
  for (int kt = 0; kt < ntiles; kt += 2) {
    if (kt + 1 < ntiles) load_tile(kt + 1, kB0, kB1, vB0, vB1);
    compute_tile(kt, kA0, kA1, vA0, vA1);
    if (kt + 1 >= ntiles) break;
    if (kt + 2 < ntiles) load_tile(kt + 2, kA0, kA1, vA0, vA1);
    compute_tile(kt + 1, kB0, kB1, vB0, vB1);
  }

  // epilogue: O^T (regs) -> LDS transpose -> coalesced stores
  const float rl = (l_run > 0.f) ? 1.0f / l_run : 0.f;
#pragma unroll
  for (int dt = 0; dt < 2; dt++)
#pragma unroll
    for (int r = 0; r < 16; r++) {
      int chunk = dt * 4 + (r >> 2);
      int el = (r & 3) + 4 * hi;
      Ot[l31 * 64 + ((chunk ^ (l31 & 7)) * 8) + el] = (__bf16)(oT[dt][r] * rl);
    }
  __syncthreads();
#pragma unroll
  for (int it = 0; it < 4; it++) {
    int qr2 = (lane >> 3) + it * 8;
    int cc = lane & 7;
    bf16x8 v = *(const bf16x8*)(Ot + qr2 * 64 + ((cc ^ (qr2 & 7)) * 8));
    *(bf16x8*)(&O[(size_t)(b * S_ + q0 + qr2) * D_ + h * 64 + cc * 8]) = v;
  }
}

extern "C" void kernel_launch(void* const* d_in, const int* in_sizes, int n_in,
                              void* d_out, int out_size, void* d_ws, size_t ws_size,
                              hipStream_t stream) {
  const float* inputs = (const float*)d_in[0];
  const int* positions = (const int*)d_in[1];
  const float* W_in = (const float*)d_in[2];
  const float* W_out = (const float*)d_in[3];
  float* out = (float*)d_out;

  bf16_t* X_bf = (bf16_t*)d_ws;
  bf16_t* Win_bf = X_bf + (size_t)4096 * 1024;
  bf16_t* Wout_bf = Win_bf + (size_t)3072 * 1024;
  bf16_t* qkv_bf = Wout_bf + (size_t)1024 * 1024;
  bf16_t* Qb = qkv_bf + (size_t)4096 * 3072;
  bf16_t* Kb = Qb + (size_t)B_ * H_ * S_ * HD_;
  bf16_t* Vtb = Kb + (size_t)B_ * H_ * S_ * HD_;
  bf16_t* Ob = Vtb + (size_t)B_ * H_ * S_ * HD_;

  cast_bf16_kernel<<<dim3(2048), dim3(256), 0, stream>>>(inputs, X_bf, (4096 * 1024) / 4);
  cast_bf16_kernel<<<dim3(2048), dim3(256), 0, stream>>>(W_in, Win_bf, (3072 * 1024) / 4);
  cast_bf16_kernel<<<dim3(1024), dim3(256), 0, stream>>>(W_out, Wout_bf, (1024 * 1024) / 4);

  gemm_bt<bf16_t><<<dim3(32, 24), dim3(256), 0, stream>>>(X_bf, Win_bf, qkv_bf, 4096, 3072, 1024);

  rope_qk_kernel<<<dim3((B_ * S_ * H_ * 32) / 256), dim3(256), 0, stream>>>(qkv_bf, positions, Qb, Kb);
  v_transpose_kernel<<<dim3(S_ / 64, H_, B_), dim3(256), 0, stream>>>(qkv_bf, Vtb);

  attn_kernel<<<dim3(S_ / 32, H_, B_), dim3(64), 0, stream>>>(Qb, Kb, Vtb, positions, Ob);

  gemm_bt<float><<<dim3(32, 8), dim3(256), 0, stream>>>(Ob, Wout_bf, out, 4096, 1024, 1024);
}

// Round 7
// 161.667 us; speedup vs baseline: 1.4434x; 1.4434x over previous
//
#include <hip/hip_runtime.h>
#include <stdint.h>
#include <math.h>

#define B_ 2
#define S_ 2048
#define D_ 1024
#define H_ 16
#define HD_ 64
#define KVBLK 64

typedef __bf16 bf16_t;
typedef __bf16 bf16x4 __attribute__((ext_vector_type(4)));
typedef __bf16 bf16x8 __attribute__((ext_vector_type(8)));
typedef float f32x4 __attribute__((ext_vector_type(4)));
typedef float f32x16 __attribute__((ext_vector_type(16)));
typedef float float4v __attribute__((ext_vector_type(4)));

#define L2E 1.4426950408889634f
#define NINF (-__builtin_inff())

__device__ __forceinline__ void gload_lds16(const bf16_t* g, bf16_t* l) {
  __builtin_amdgcn_global_load_lds((const __attribute__((address_space(1))) void*)g,
                                   (__attribute__((address_space(3))) void*)l, 16, 0, 0);
}

__device__ __forceinline__ uint32_t packbf(float a, float b) {
  union { __bf16 h[2]; uint32_t u; } cvt;
  cvt.h[0] = (__bf16)a; cvt.h[1] = (__bf16)b;
  return cvt.u;
}

// ---------------- cast f32 -> bf16 (vector x4) ----------------
__global__ void cast_bf16_kernel(const float* __restrict__ src, bf16_t* __restrict__ dst, int n4) {
  int i = blockIdx.x * blockDim.x + threadIdx.x;
  int stride = gridDim.x * blockDim.x;
  for (; i < n4; i += stride) {
    float4v f = *(const float4v*)(src + (size_t)i * 4);
    bf16x4 o;
    o[0] = (__bf16)f[0]; o[1] = (__bf16)f[1]; o[2] = (__bf16)f[2]; o[3] = (__bf16)f[3];
    *(bf16x4*)(dst + (size_t)i * 4) = o;
  }
}

// ---------------- GEMM: C[m][n] = sum_k A[m][k] * B[n][k] ----------------
template <typename OutT>
__global__ __launch_bounds__(256) void gemm_bt(const bf16_t* __restrict__ A,
                                               const bf16_t* __restrict__ Bm,
                                               OutT* __restrict__ C,
                                               int M, int N, int K) {
  __shared__ bf16_t As[128 * 32];
  __shared__ bf16_t Bs[128 * 32];
  const int t = threadIdx.x;
  const int lane = t & 63, wave = t >> 6;
  const int wr = wave >> 1, wc = wave & 1;
  const int qr = lane & 15, g = lane >> 4;
  const int bm = blockIdx.x, bn = blockIdx.y;

  f32x4 acc[4][4];
#pragma unroll
  for (int m = 0; m < 4; m++)
#pragma unroll
    for (int n = 0; n < 4; n++) acc[m][n] = (f32x4){0.f, 0.f, 0.f, 0.f};

  const bf16_t* Abase = A + (size_t)(bm * 128) * K;
  const bf16_t* Bbase = Bm + (size_t)(bn * 128) * K;
  const int srow = t >> 2;
  const int scol = (t & 3) * 8;

  for (int kk = 0; kk < K; kk += 32) {
    gload_lds16(Abase + (size_t)srow * K + kk + scol,        As + t * 8);
    gload_lds16(Abase + (size_t)(srow + 64) * K + kk + scol, As + 2048 + t * 8);
    gload_lds16(Bbase + (size_t)srow * K + kk + scol,        Bs + t * 8);
    gload_lds16(Bbase + (size_t)(srow + 64) * K + kk + scol, Bs + 2048 + t * 8);
    __syncthreads();
    bf16x8 a[4], b[4];
#pragma unroll
    for (int m = 0; m < 4; m++)
      a[m] = *(const bf16x8*)(As + (wr * 64 + m * 16 + qr) * 32 + g * 8);
#pragma unroll
    for (int n = 0; n < 4; n++)
      b[n] = *(const bf16x8*)(Bs + (wc * 64 + n * 16 + qr) * 32 + g * 8);
#pragma unroll
    for (int m = 0; m < 4; m++)
#pragma unroll
      for (int n = 0; n < 4; n++)
        acc[m][n] = __builtin_amdgcn_mfma_f32_16x16x32_bf16(a[m], b[n], acc[m][n], 0, 0, 0);
    __syncthreads();
  }

#pragma unroll
  for (int m = 0; m < 4; m++) {
    int row0 = bm * 128 + wr * 64 + m * 16 + g * 4;
#pragma unroll
    for (int n = 0; n < 4; n++) {
      int col = bn * 128 + wc * 64 + n * 16 + qr;
#pragma unroll
      for (int r = 0; r < 4; r++)
        C[(size_t)(row0 + r) * N + col] = (OutT)acc[m][n][r];
    }
  }
}

// ---------------- RoPE on q,k + q-scale; writes Q,K as [B][H][S][HD] bf16 ----------------
__global__ void rope_qk_kernel(const bf16_t* __restrict__ qkv, const int* __restrict__ pos,
                               bf16_t* __restrict__ Q, bf16_t* __restrict__ Ko) {
  int idx = blockIdx.x * blockDim.x + threadIdx.x;
  if (idx >= B_ * S_ * H_ * 32) return;
  int i = idx & 31;
  int h = (idx >> 5) & (H_ - 1);
  int bs = idx >> 9;
  const bf16_t* row = qkv + (size_t)bs * (3 * D_) + h * 192;
  float q1 = (float)row[i], q2 = (float)row[i + 32];
  float k1 = (float)row[64 + i], k2 = (float)row[96 + i];
  int p = pos[bs];
  float inv = exp2f(-(float)i * (13.287712379549449f / 32.0f));
  float ang = (float)p * inv;
  float sn, cs;
  sincosf(ang, &sn, &cs);
  float qo1 = (q1 * cs - q2 * sn) * 0.125f;
  float qo2 = (q2 * cs + q1 * sn) * 0.125f;
  float ko1 = k1 * cs - k2 * sn;
  float ko2 = k2 * cs + k1 * sn;
  int b = bs >> 11, s = bs & (S_ - 1);
  size_t o = ((size_t)(b * H_ + h) * S_ + s) * HD_ + i;
  Q[o] = (__bf16)qo1;  Q[o + 32] = (__bf16)qo2;
  Ko[o] = (__bf16)ko1; Ko[o + 32] = (__bf16)ko2;
}

// ---------------- V transpose: qkv v-slice -> Vt [B][H][HD][S] bf16 ----------------
__global__ __launch_bounds__(256) void v_transpose_kernel(const bf16_t* __restrict__ qkv,
                                                          bf16_t* __restrict__ Vt) {
  __shared__ bf16_t tile[64][72];
  int t = threadIdx.x;
  int s0 = blockIdx.x * 64;
  int h = blockIdx.y, b = blockIdx.z;
  int sl = t >> 4;
  int cb = (t & 15) * 4;
#pragma unroll
  for (int it = 0; it < 4; it++) {
    int s = sl + it * 16;
    const bf16_t* src = qkv + (size_t)(b * S_ + s0 + s) * (3 * D_) + h * 192 + 128 + cb;
    bf16x4 v = *(const bf16x4*)src;
    tile[cb + 0][s] = v[0]; tile[cb + 1][s] = v[1];
    tile[cb + 2][s] = v[2]; tile[cb + 3][s] = v[3];
  }
  __syncthreads();
#pragma unroll
  for (int it = 0; it < 4; it++) {
    int d = sl + it * 16;
    bf16x4 v;
    v[0] = tile[d][cb]; v[1] = tile[d][cb + 1]; v[2] = tile[d][cb + 2]; v[3] = tile[d][cb + 3];
    *(bf16x4*)(Vt + ((size_t)((b * H_ + h) * HD_ + d)) * S_ + s0 + cb) = v;
  }
}

// ---------------- flash attention: 4-wave LDS-dbuf + XCD-resident KV mapping ----------------
// 1-D grid of 512. bid -> XCD is round-robin (bid & 7, m09); we pin each (b,h) pair's
// 16 q-blocks to ONE XCD so its 512 KB KV stays L2-resident (4 bh x 512 KB = 2 MB < 4 MB L2).
//   bh   = (bid & 7) * 4 + ((bid >> 3) & 3)   // 4 bh per XCD
//   qblk = 15 - (bid >> 5)                    // heavy q-blocks dispatch first
// 256 threads = 4 waves; wave wv owns q rows [q0+wv*32,+32). Swapped QK^T / swapped PV,
// K/V double-buffered in LDS, prefetch of tile t+1 issued before compute(t).
__global__ __launch_bounds__(256) void attn_kernel(const bf16_t* __restrict__ Q,
                                                   const bf16_t* __restrict__ K,
                                                   const bf16_t* __restrict__ Vt,
                                                   const int* __restrict__ pos,
                                                   bf16_t* __restrict__ O) {
  __shared__ bf16_t Ks[2][64 * 64];   // [buf][k][d] 16B-chunk XOR swizzled
  __shared__ bf16_t Vs[2][64 * 64];   // [buf][d][s] 16B-chunk XOR swizzled

  const int t = threadIdx.x;
  const int lane = t & 63, wv = t >> 6;
  const int l31 = lane & 31, hi = lane >> 5;

  const int bid = blockIdx.x;
  const int bh = (bid & 7) * 4 + ((bid >> 3) & 3);
  const int qblk = 15 - (bid >> 5);
  const int b = bh >> 4, h = bh & 15;
  const int q0 = qblk * 128;

  const bf16_t* Qb = Q + (size_t)bh * (S_ * HD_);
  const bf16_t* Kb = K + (size_t)bh * (S_ * HD_);
  const bf16_t* Vb = Vt + (size_t)bh * (HD_ * S_);

  // Q fragments (B-operand): lane holds row q = q0+wv*32+l31, d = c*16 + 8*hi + j
  const int qrow = q0 + wv * 32 + l31;
  bf16x8 qf[4];
#pragma unroll
  for (int c = 0; c < 4; c++)
    qf[c] = *(const bf16x8*)(Qb + (size_t)qrow * HD_ + c * 16 + hi * 8);

  const int prow = pos[b * S_ + qrow];
  int wmin = prow;
#pragma unroll
  for (int off = 1; off < 32; off <<= 1) wmin = min(wmin, __shfl_xor(wmin, off));

  int mp = max(pos[b * S_ + q0 + lane], pos[b * S_ + q0 + 64 + lane]);
#pragma unroll
  for (int off = 1; off < 64; off <<= 1) mp = max(mp, __shfl_xor(mp, off));
  const int ntiles = min(S_ / KVBLK, (mp >> 6) + 1);

  // staging bases (per-thread constant)
  const int r0 = t >> 3, c0 = t & 7;
  const int r1 = (t + 256) >> 3, c1 = t & 7;
  const bf16_t* KgA = Kb + (size_t)r0 * HD_ + ((c0 ^ (r0 & 7)) * 8);
  const bf16_t* KgB = Kb + (size_t)r1 * HD_ + ((c1 ^ (r1 & 7)) * 8);
  const bf16_t* VgA = Vb + (size_t)r0 * S_ + ((c0 ^ (r0 & 7)) * 8);
  const bf16_t* VgB = Vb + (size_t)r1 * S_ + ((c1 ^ (r1 & 7)) * 8);
  const int ldsA = t * 8, ldsB = (t + 256) * 8;

  f32x16 oT[2];
#pragma unroll
  for (int dt = 0; dt < 2; dt++)
#pragma unroll
    for (int r = 0; r < 16; r++) oT[dt][r] = 0.f;
  float m_run = NINF, l_run = 0.f;

  // prologue: stage tile 0 into buf 0
  gload_lds16(KgA, Ks[0] + ldsA);
  gload_lds16(KgB, Ks[0] + ldsB);
  gload_lds16(VgA, Vs[0] + ldsA);
  gload_lds16(VgB, Vs[0] + ldsB);
  __syncthreads();

  for (int kt = 0; kt < ntiles; ++kt) {
    const int k0 = kt * KVBLK;
    const int cur = kt & 1;
    if (kt + 1 < ntiles) {
      const int kn = (kt + 1) * KVBLK;
      gload_lds16(KgA + (size_t)kn * HD_, Ks[cur ^ 1] + ldsA);
      gload_lds16(KgB + (size_t)kn * HD_, Ks[cur ^ 1] + ldsB);
      gload_lds16(VgA + kn, Vs[cur ^ 1] + ldsA);
      gload_lds16(VgB + kn, Vs[cur ^ 1] + ldsB);
    }
    const bf16_t* Kc = Ks[cur];
    const bf16_t* Vc = Vs[cur];

    // QK^T swapped
    f32x16 s0, s1;
#pragma unroll
    for (int r = 0; r < 16; r++) { s0[r] = 0.f; s1[r] = 0.f; }
    __builtin_amdgcn_s_setprio(1);
#pragma unroll
    for (int c = 0; c < 4; c++) {
      const int c2 = c * 2 + hi;
      const int kr0 = l31;
      const int kr1 = 32 + l31;
      bf16x8 kf0 = *(const bf16x8*)(Kc + kr0 * 64 + ((c2 ^ (kr0 & 7)) * 8));
      bf16x8 kf1 = *(const bf16x8*)(Kc + kr1 * 64 + ((c2 ^ (kr1 & 7)) * 8));
      s0 = __builtin_amdgcn_mfma_f32_32x32x16_bf16(kf0, qf[c], s0, 0, 0, 0);
      s1 = __builtin_amdgcn_mfma_f32_32x32x16_bf16(kf1, qf[c], s1, 0, 0, 0);
    }
    __builtin_amdgcn_s_setprio(0);

    // mask (skip when tile fully visible for this wave)
    float p0[16], p1[16];
    if (k0 + 63 > wmin) {
#pragma unroll
      for (int r = 0; r < 16; r++) {
        int koff = (r & 3) + 8 * (r >> 2) + 4 * hi;
        p0[r] = (k0 + koff <= prow) ? s0[r] : NINF;
        p1[r] = (k0 + 32 + koff <= prow) ? s1[r] : NINF;
      }
    } else {
#pragma unroll
      for (int r = 0; r < 16; r++) { p0[r] = s0[r]; p1[r] = s1[r]; }
    }

    // per-lane online softmax with defer-max (T13, THR=8)
    float tm = NINF;
#pragma unroll
    for (int r = 0; r < 16; r++) tm = fmaxf(tm, fmaxf(p0[r], p1[r]));
    tm = fmaxf(tm, __shfl_xor(tm, 32));
    if (__any(tm > m_run + 8.0f)) {
      float mn = fmaxf(fmaxf(m_run, tm), -1e30f);
      float scale = exp2f((m_run - mn) * L2E);
      l_run *= scale;
#pragma unroll
      for (int dt = 0; dt < 2; dt++)
#pragma unroll
        for (int r = 0; r < 16; r++) oT[dt][r] *= scale;
      m_run = mn;
    }
    const float mnl = m_run * L2E;
    float rs = 0.f;
#pragma unroll
    for (int r = 0; r < 16; r++) {
      p0[r] = exp2f(p0[r] * L2E - mnl);
      p1[r] = exp2f(p1[r] * L2E - mnl);
      rs += p0[r] + p1[r];
    }
    rs += __shfl_xor(rs, 32);
    l_run += rs;

    // PV swapped: oT[dt] += V^T(32d x 16k) x P(16k x 32q)
#pragma unroll
    for (int kc = 0; kc < 4; kc++) {
      const float* P = (kc < 2) ? p0 : p1;
      const int rb = (kc & 1) * 8;
      uint32_t xa0 = packbf(P[rb + 0], P[rb + 1]);
      uint32_t xa1 = packbf(P[rb + 2], P[rb + 3]);
      uint32_t xb0 = packbf(P[rb + 4], P[rb + 5]);
      uint32_t xb1 = packbf(P[rb + 6], P[rb + 7]);
      uint32_t sa0 = (uint32_t)__shfl_xor((int)xa0, 32);
      uint32_t sa1 = (uint32_t)__shfl_xor((int)xa1, 32);
      uint32_t sb0 = (uint32_t)__shfl_xor((int)xb0, 32);
      uint32_t sb1 = (uint32_t)__shfl_xor((int)xb1, 32);
      union { uint32_t u[4]; bf16x8 v; } pf;
      pf.u[0] = hi ? sb0 : xa0;
      pf.u[1] = hi ? sb1 : xa1;
      pf.u[2] = hi ? xb0 : sa0;
      pf.u[3] = hi ? xb1 : sa1;
      __builtin_amdgcn_s_setprio(1);
#pragma unroll
      for (int dt = 0; dt < 2; dt++) {
        const int vr = dt * 32 + l31;
        const int c2 = kc * 2 + hi;
        bf16x8 vf = *(const bf16x8*)(Vc + vr * 64 + ((c2 ^ (vr & 7)) * 8));
        oT[dt] = __builtin_amdgcn_mfma_f32_32x32x16_bf16(vf, pf.v, oT[dt], 0, 0, 0);
      }
      __builtin_amdgcn_s_setprio(0);
    }

    __syncthreads();  // drains this iter's prefetch (issued pre-compute) + joins waves
  }

  // epilogue: O^T (regs) -> LDS transpose -> coalesced global stores
  const float rl = (l_run > 0.f) ? 1.0f / l_run : 0.f;
  bf16_t* Ot = (bf16_t*)Ks + wv * 2048;  // 4 waves x [32 q][64 d] swizzled = 16KB
#pragma unroll
  for (int dt = 0; dt < 2; dt++)
#pragma unroll
    for (int r = 0; r < 16; r++) {
      int chunk = dt * 4 + (r >> 2);
      int el = (r & 3) + 4 * hi;
      Ot[l31 * 64 + ((chunk ^ (l31 & 7)) * 8) + el] = (__bf16)(oT[dt][r] * rl);
    }
  __syncthreads();
#pragma unroll
  for (int it = 0; it < 4; it++) {
    int qr2 = (lane >> 3) + it * 8;
    int cc = lane & 7;
    bf16x8 v = *(const bf16x8*)(Ot + qr2 * 64 + ((cc ^ (qr2 & 7)) * 8));
    *(bf16x8*)(&O[(size_t)(b * S_ + q0 + wv * 32 + qr2) * D_ + h * 64 + cc * 8]) = v;
  }
}

extern "C" void kernel_launch(void* const* d_in, const int* in_sizes, int n_in,
                              void* d_out, int out_size, void* d_ws, size_t ws_size,
                              hipStream_t stream) {
  const float* inputs = (const float*)d_in[0];
  const int* positions = (const int*)d_in[1];
  const float* W_in = (const float*)d_in[2];
  const float* W_out = (const float*)d_in[3];
  float* out = (float*)d_out;

  bf16_t* X_bf = (bf16_t*)d_ws;
  bf16_t* Win_bf = X_bf + (size_t)4096 * 1024;
  bf16_t* Wout_bf = Win_bf + (size_t)3072 * 1024;
  bf16_t* qkv_bf = Wout_bf + (size_t)1024 * 1024;
  bf16_t* Qb = qkv_bf + (size_t)4096 * 3072;
  bf16_t* Kb = Qb + (size_t)B_ * H_ * S_ * HD_;
  bf16_t* Vtb = Kb + (size_t)B_ * H_ * S_ * HD_;
  bf16_t* Ob = Vtb + (size_t)B_ * H_ * S_ * HD_;

  cast_bf16_kernel<<<dim3(2048), dim3(256), 0, stream>>>(inputs, X_bf, (4096 * 1024) / 4);
  cast_bf16_kernel<<<dim3(2048), dim3(256), 0, stream>>>(W_in, Win_bf, (3072 * 1024) / 4);
  cast_bf16_kernel<<<dim3(1024), dim3(256), 0, stream>>>(W_out, Wout_bf, (1024 * 1024) / 4);

  gemm_bt<bf16_t><<<dim3(32, 24), dim3(256), 0, stream>>>(X_bf, Win_bf, qkv_bf, 4096, 3072, 1024);

  rope_qk_kernel<<<dim3((B_ * S_ * H_ * 32) / 256), dim3(256), 0, stream>>>(qkv_bf, positions, Qb, Kb);
  v_transpose_kernel<<<dim3(S_ / 64, H_, B_), dim3(256), 0, stream>>>(qkv_bf, Vtb);

  attn_kernel<<<dim3(512), dim3(256), 0, stream>>>(Qb, Kb, Vtb, positions, Ob);

  gemm_bt<float><<<dim3(32, 8), dim3(256), 0, stream>>>(Ob, Wout_bf, out, 4096, 1024, 1024);
}